// Round 2
// baseline (3463.199 us; speedup 1.0000x reference)
//
#include <hip/hip_runtime.h>
#include <cstdint>
#include <cstddef>

// QLSTM on MI355X. Persistent kernel, 64 WGs (4 batch-groups x 16 hidden-
// slices), 1 block/CU (64 blocks << 256 CUs -> co-residency by capacity; no
// cooperative launch, which fails under graph capture). Weights resident in
// VGPRs (bf16 B-fragments); per-step sync via per-batch-group release/acquire
// flags; h ping-pong (bf16) in d_ws.

#define SEQ 512
#define BATCH 256
#define IN_DIMX 256
#define HIDN 256
#define DTOT 512

typedef float f32x4 __attribute__((ext_vector_type(4)));
typedef short s16x8 __attribute__((ext_vector_type(8)));

__device__ __forceinline__ unsigned short f2bf(float f) {
  unsigned u = __builtin_bit_cast(unsigned, f);
  u += 0x7FFFu + ((u >> 16) & 1u);   // RNE to bf16
  return (unsigned short)(u >> 16);
}

__device__ __forceinline__ float sigm(float x) {
  return __builtin_amdgcn_rcpf(1.0f + __expf(-x));
}
__device__ __forceinline__ float tanh_fast(float x) {
  return 1.0f - 2.0f * __builtin_amdgcn_rcpf(1.0f + __expf(2.0f * x));
}

// hbuf[0] <- h0 (bf16, [bm4][kc32][row64][8] layout), zero the flag array.
__global__ void qlstm_prep(const float* __restrict__ h0,
                           unsigned short* __restrict__ hbuf,
                           int* __restrict__ flags) {
  int tid = blockIdx.x * blockDim.x + threadIdx.x;   // 65536 threads
  if (tid < (SEQ + 2) * 4) flags[tid] = 0;
  int bm = tid >> 14, kc = (tid >> 9) & 31, row = (tid >> 3) & 63, j = tid & 7;
  hbuf[tid] = f2bf(h0[(bm * 64 + row) * HIDN + kc * 8 + j]);
}

__launch_bounds__(256, 1)
__global__ void qlstm_main(
    const float* __restrict__ X, const float* __restrict__ c0,
    const float* __restrict__ Wf, const float* __restrict__ bf_,
    const float* __restrict__ thf, const float* __restrict__ scf,
    const float* __restrict__ Wi, const float* __restrict__ bi_,
    const float* __restrict__ thi, const float* __restrict__ sci,
    const float* __restrict__ Wu, const float* __restrict__ bu_,
    const float* __restrict__ thu, const float* __restrict__ scu,
    const float* __restrict__ Wo, const float* __restrict__ bo_,
    const float* __restrict__ tho, const float* __restrict__ sco,
    float* __restrict__ out,
    unsigned short* __restrict__ hbuf,
    int* __restrict__ flags) {
  // staged h(t): [kc32][row64][8 bf16] -> A-frag ds_read_b128 is conflict-free
  __shared__ __align__(16) unsigned short hA[32 * 64 * 8];

  const int tid = threadIdx.x;
  const int wave = tid >> 6;
  const int lane = tid & 63;
  const int quad = lane >> 4;
  const int col = lane & 15;          // MFMA n-index / C col / A m-index
  const int bm = blockIdx.x & 3;      // batch group (64 rows)
  const int js = blockIdx.x >> 2;     // hidden slice (16 cols)

  // ---- resident weight fragments (bf16), loaded once ----
  // B-frag for 16x16x32: B[k = quad*8 + j][n = col]; B[k][n] = W_g[js*16+n][k]
  s16x8 wx[4][8], wh[4][8];   // 256 VGPRs
  {
    const float* Wg[4] = {Wf, Wi, Wu, Wo};
#pragma unroll
    for (int g = 0; g < 4; ++g) {
      const float* wr = Wg[g] + (size_t)(js * 16 + col) * DTOT + quad * 8;
#pragma unroll
      for (int s = 0; s < 16; ++s) {
        float4 p0 = *(const float4*)(wr + s * 32);
        float4 p1 = *(const float4*)(wr + s * 32 + 4);
        s16x8 fr;
        fr[0] = (short)f2bf(p0.x); fr[1] = (short)f2bf(p0.y);
        fr[2] = (short)f2bf(p0.z); fr[3] = (short)f2bf(p0.w);
        fr[4] = (short)f2bf(p1.x); fr[5] = (short)f2bf(p1.y);
        fr[6] = (short)f2bf(p1.z); fr[7] = (short)f2bf(p1.w);
        if (s < 8) wx[g][s] = fr; else wh[g][s - 8] = fr;
      }
    }
  }
  float th[4], sc[4], bi[4];
  {
    const float* Tg[4] = {thf, thi, thu, tho};
    const float* Sg[4] = {scf, sci, scu, sco};
    const float* Bg[4] = {bf_, bi_, bu_, bo_};
#pragma unroll
    for (int g = 0; g < 4; ++g) {
      th[g] = Tg[g][js * 16 + col];
      sc[g] = Sg[g][js * 16 + col];
      bi[g] = Bg[g][js * 16 + col];
    }
  }

  // c state: C/D layout row = quad*4 + r, col = lane&15
  const int browq = bm * 64 + wave * 16 + quad * 4;
  float c[4];
#pragma unroll
  for (int r = 0; r < 4; ++r)
    c[r] = c0[(size_t)(browq + r) * HIDN + js * 16 + col];

  const float* Xrow = X + (size_t)(bm * 64 + wave * 16 + col) * IN_DIMX + quad * 8;
  const int kc_out = js * 2 + (col >> 3);
  const int jsub = col & 7;

#pragma clang loop unroll(disable)
  for (int t = 0; t < SEQ; ++t) {
    // issue x loads first; their latency hides under the flag spin
    float4 xv[8][2];
    {
      const float* xb = Xrow + (size_t)t * BATCH * IN_DIMX;
#pragma unroll
      for (int s = 0; s < 8; ++s) {
        xv[s][0] = *(const float4*)(xb + s * 32);
        xv[s][1] = *(const float4*)(xb + s * 32 + 4);
      }
    }
    if (t > 0) {
      if (tid == 0) {
        while (__hip_atomic_load(&flags[t * 4 + bm], __ATOMIC_ACQUIRE,
                                 __HIP_MEMORY_SCOPE_AGENT) < 16) {
          __builtin_amdgcn_s_sleep(2);
        }
      }
      __syncthreads();
    }
    // stage h(t) tile: 32 KB linear copy (chunk order == LDS order)
    {
      const unsigned short* hsrc = hbuf + ((size_t)((t & 1) * 4 + bm)) * 16384;
#pragma unroll
      for (int i = 0; i < 8; ++i) {
        int idx = i * 256 + tid;
        *(uint4*)&hA[idx * 8] = *(const uint4*)(hsrc + idx * 8);
      }
    }
    __syncthreads();

    // convert x to bf16 A-fragments: A[m=col][k = quad*8 + j]
    s16x8 xf[8];
#pragma unroll
    for (int s = 0; s < 8; ++s) {
      s16x8 fr;
      fr[0] = (short)f2bf(xv[s][0].x); fr[1] = (short)f2bf(xv[s][0].y);
      fr[2] = (short)f2bf(xv[s][0].z); fr[3] = (short)f2bf(xv[s][0].w);
      fr[4] = (short)f2bf(xv[s][1].x); fr[5] = (short)f2bf(xv[s][1].y);
      fr[6] = (short)f2bf(xv[s][1].z); fr[7] = (short)f2bf(xv[s][1].w);
      xf[s] = fr;
    }

    f32x4 acc[4];
#pragma unroll
    for (int g = 0; g < 4; ++g) acc[g] = (f32x4){bi[g], bi[g], bi[g], bi[g]};

#pragma unroll
    for (int s = 0; s < 8; ++s) {
#pragma unroll
      for (int g = 0; g < 4; ++g)
        acc[g] = __builtin_amdgcn_mfma_f32_16x16x32_bf16(xf[s], wx[g][s], acc[g], 0, 0, 0);
    }
#pragma unroll
    for (int s = 0; s < 8; ++s) {
      s16x8 af = *(const s16x8*)&hA[((s * 4 + quad) * 64 + wave * 16 + col) * 8];
#pragma unroll
      for (int g = 0; g < 4; ++g)
        acc[g] = __builtin_amdgcn_mfma_f32_16x16x32_bf16(af, wh[g][s], acc[g], 0, 0, 0);
    }

    // gates + state update; acc tiles 0..3 = f,i,u,o at identical (b,j)
    unsigned short* hdst = hbuf + ((size_t)(((t + 1) & 1) * 4 + bm)) * 16384;
    float* orow = out + (size_t)t * BATCH * HIDN;
#pragma unroll
    for (int r = 0; r < 4; ++r) {
      float fg = sigm(sigm(__sinf(acc[0][r] * th[0]) * sc[0]));
      float ig = sigm(sigm(__sinf(acc[1][r] * th[1]) * sc[1]));
      float gg = tanh_fast(sigm(__sinf(acc[2][r] * th[2]) * sc[2]));
      float og = sigm(sigm(__sinf(acc[3][r] * th[3]) * sc[3]));
      float cn = fg * c[r] + ig * gg;
      c[r] = cn;
      float hh = og * tanh_fast(cn);
      int brow = browq + r;
      orow[(size_t)brow * HIDN + js * 16 + col] = hh;
      hdst[(kc_out * 64 + (wave * 16 + quad * 4 + r)) * 8 + jsub] = f2bf(hh);
      if (t == SEQ - 1) {
        out[(size_t)SEQ * BATCH * HIDN + (size_t)brow * HIDN + js * 16 + col] = hh;
        out[(size_t)SEQ * BATCH * HIDN + (size_t)BATCH * HIDN +
            (size_t)brow * HIDN + js * 16 + col] = cn;
      }
    }
    // publish h(t+1): drain stores (syncthreads waits vmcnt(0)), then
    // agent-scope release add by one thread (forces L2 writeback to coherent pt)
    __syncthreads();
    if (tid == 0)
      __hip_atomic_fetch_add(&flags[(t + 1) * 4 + bm], 1, __ATOMIC_RELEASE,
                             __HIP_MEMORY_SCOPE_AGENT);
  }
}

extern "C" void kernel_launch(void* const* d_in, const int* in_sizes, int n_in,
                              void* d_out, int out_size, void* d_ws, size_t ws_size,
                              hipStream_t stream) {
  (void)in_sizes; (void)n_in; (void)out_size; (void)ws_size;
  const float* X   = (const float*)d_in[0];
  const float* h0  = (const float*)d_in[1];
  const float* c0  = (const float*)d_in[2];
  const float* Wf  = (const float*)d_in[3];
  const float* bf_ = (const float*)d_in[4];
  const float* thf = (const float*)d_in[5];
  const float* scf = (const float*)d_in[6];
  const float* Wi  = (const float*)d_in[7];
  const float* bi_ = (const float*)d_in[8];
  const float* thi = (const float*)d_in[9];
  const float* sci = (const float*)d_in[10];
  const float* Wu  = (const float*)d_in[11];
  const float* bu_ = (const float*)d_in[12];
  const float* thu = (const float*)d_in[13];
  const float* scu = (const float*)d_in[14];
  const float* Wo  = (const float*)d_in[15];
  const float* bo_ = (const float*)d_in[16];
  const float* tho = (const float*)d_in[17];
  const float* sco = (const float*)d_in[18];
  float* out = (float*)d_out;

  unsigned short* hbuf = (unsigned short*)d_ws;            // 2*4*16384 u16 = 256 KB
  int* flags = (int*)((char*)d_ws + 262144);               // (SEQ+2)*4 ints

  hipLaunchKernelGGL(qlstm_prep, dim3(256), dim3(256), 0, stream, h0, hbuf, flags);

  // Plain launch: 64 blocks, 1 block/CU -> all resident on a 256-CU device.
  // (hipLaunchCooperativeKernel is rejected under graph capture -> R0/R1 no-op.)
  hipLaunchKernelGGL(qlstm_main, dim3(64), dim3(256), 0, stream,
                     X, c0, Wf, bf_, thf, scf, Wi, bi_, thi, sci,
                     Wu, bu_, thu, scu, Wo, bo_, tho, sco,
                     out, hbuf, flags);
}